// Round 9
// baseline (276.217 us; speedup 1.0000x reference)
//
#include <hip/hip_runtime.h>
#include <hip/hip_bf16.h>
#include <math.h>

// Problem constants
#define B_   2
#define S_   2048
#define DM_  1024
#define H_   16
#define HD_  64
#define MEM_ 1000
#define KTOT 10
#define NROW (B_ * S_)          // 4096
#define NEG9 (-1e9f)
#define LDK  72                 // bf16 row stride in attention LDS tiles
#define NITEMS 1024             // attention work items: 32 qt x 16 h x 2 b

typedef __attribute__((ext_vector_type(8))) short short8;
typedef __attribute__((ext_vector_type(4))) float f32x4;

// async global->LDS, 16B per lane, dest = wave-uniform base + lane*16
__device__ __forceinline__ void gll16(const __hip_bfloat16* g, __hip_bfloat16* l) {
    __builtin_amdgcn_global_load_lds(
        (const __attribute__((address_space(1))) void*)g,
        (__attribute__((address_space(3))) void*)l, 16, 0, 0);
}

// ---------------------------------------------------------------------------
// prep: fused prologue (independent parts, branch on block range).
//   blocks [0,2048):    inputs fp32 -> bf16 Ax
//   blocks [2048,3072): weights fp32 -> transposed bf16 Wt[g*1024+n][k]
//   blocks [3072,3104): last-row K in fp32 (retrieval stays exact)
//   block 0 thread 0:   zero the work-steal counter + sims-done counter
// ---------------------------------------------------------------------------
__global__ __launch_bounds__(256) void prep(const float* __restrict__ inputs,
                                            const float* __restrict__ Wq,
                                            const float* __restrict__ Wk,
                                            const float* __restrict__ Wv,
                                            const float* __restrict__ Wo,
                                            __hip_bfloat16* __restrict__ Ax,
                                            __hip_bfloat16* __restrict__ Wt,
                                            float* __restrict__ lk,
                                            int* __restrict__ ctr) {
    const int bx = blockIdx.x, tid = threadIdx.x;
    if (bx == 0 && tid == 0) { ctr[0] = 0; ctr[1] = 0; }

    if (bx < 2048) {
        const size_t i = ((size_t)bx * 256 + tid) * 8;
        float4 a = *(const float4*)&inputs[i];
        float4 b = *(const float4*)&inputs[i + 4];
        alignas(16) __hip_bfloat16 t[8];
        t[0] = __float2bfloat16(a.x); t[1] = __float2bfloat16(a.y);
        t[2] = __float2bfloat16(a.z); t[3] = __float2bfloat16(a.w);
        t[4] = __float2bfloat16(b.x); t[5] = __float2bfloat16(b.y);
        t[6] = __float2bfloat16(b.z); t[7] = __float2bfloat16(b.w);
        *(short8*)&Ax[i] = *(short8*)t;
        return;
    }
    if (bx < 3072) {
        const int idx = bx - 2048;
        const int g = idx >> 8, rem = idx & 255;
        const float* W = (g == 0) ? Wq : (g == 1) ? Wk : (g == 2) ? Wv : Wo;
        const int n0 = (rem & 15) * 64, k0 = (rem >> 4) * 64;
        __shared__ float T[64][65];
        {
            const int r = tid >> 4, c4 = (tid & 15) * 4;
#pragma unroll
            for (int p = 0; p < 4; ++p) {
                float4 v = *(const float4*)&W[(size_t)(k0 + r + p * 16) * 1024 + n0 + c4];
                T[r + p * 16][c4 + 0] = v.x; T[r + p * 16][c4 + 1] = v.y;
                T[r + p * 16][c4 + 2] = v.z; T[r + p * 16][c4 + 3] = v.w;
            }
        }
        __syncthreads();
        {
            const int n = tid >> 3, off = (tid & 7) * 8;
#pragma unroll
            for (int p = 0; p < 2; ++p) {
                const int nn = n + p * 32;
                alignas(16) __hip_bfloat16 t[8];
#pragma unroll
                for (int j = 0; j < 8; ++j) t[j] = __float2bfloat16(T[off + j][nn]);
                *(short8*)&Wt[((size_t)(g * 1024 + n0 + nn)) * 1024 + k0 + off] = *(short8*)t;
            }
        }
        return;
    }
    {   // lastk: lk[b,:] = inputs[b, S-1, :] @ Wk (fp32)
        const int idx = bx - 3072;
        const int xblk = idx & 15, b = idx >> 4;
        const int cl = tid & 63;
        const int col = xblk * 64 + cl;
        const int kq = tid >> 6;
        __shared__ float xr[1024];
        __shared__ float part[4][64];
        for (int i = tid; i < 1024; i += 256)
            xr[i] = inputs[((size_t)(b * S_ + S_ - 1)) * 1024 + i];
        __syncthreads();
        float acc = 0.f;
#pragma unroll 4
        for (int k = kq * 256; k < kq * 256 + 256; ++k)
            acc += xr[k] * Wk[(size_t)k * 1024 + col];
        part[kq][cl] = acc;
        __syncthreads();
        if (tid < 64)
            lk[b * 1024 + xblk * 64 + tid] =
                part[0][tid] + part[1][tid] + part[2][tid] + part[3][tid];
    }
}

// ---------------------------------------------------------------------------
// bf16 MFMA GEMM, m97 structure: BK=32, unpadded [128][32] LDS tiles staged
// with global_load_lds dwordx4. 128x128 tile, 4 waves, 16 MFMA per k-iter.
// ---------------------------------------------------------------------------
__device__ __forceinline__ void store_out(__hip_bfloat16* p, float x) { *p = __float2bfloat16(x); }
__device__ __forceinline__ void store_out(float* p, float x) { *p = x; }

template <typename OutT>
__global__ __launch_bounds__(256) void gemm_mfma(const __hip_bfloat16* __restrict__ A,
                                                 const __hip_bfloat16* __restrict__ Bt,
                                                 OutT* __restrict__ C, int ldc) {
    __shared__ __hip_bfloat16 As[128 * 32];
    __shared__ __hip_bfloat16 Bs[128 * 32];
    const int tid = threadIdx.x;
    const int wave = tid >> 6, lane = tid & 63;
    const int quad = lane >> 4, lm = lane & 15;
    const int wr = wave >> 1, wc = wave & 1;
    const int m0 = blockIdx.y * 128, n0 = blockIdx.x * 128;

    const int r0 = tid >> 2, c0 = (tid & 3) * 8;
    const __hip_bfloat16* ga0 = &A[(size_t)(m0 + r0) * 1024 + c0];
    const __hip_bfloat16* ga1 = &A[(size_t)(m0 + 64 + r0) * 1024 + c0];
    const __hip_bfloat16* gb0 = &Bt[(size_t)(n0 + r0) * 1024 + c0];
    const __hip_bfloat16* gb1 = &Bt[(size_t)(n0 + 64 + r0) * 1024 + c0];
    __hip_bfloat16* la0 = &As[(wave * 64) * 8];
    __hip_bfloat16* la1 = &As[(256 + wave * 64) * 8];
    __hip_bfloat16* lb0 = &Bs[(wave * 64) * 8];
    __hip_bfloat16* lb1 = &Bs[(256 + wave * 64) * 8];

    f32x4 acc[4][4];
#pragma unroll
    for (int i = 0; i < 4; ++i)
#pragma unroll
        for (int j = 0; j < 4; ++j) acc[i][j] = (f32x4){0.f, 0.f, 0.f, 0.f};

    for (int k0 = 0; k0 < 1024; k0 += 32) {
        __syncthreads();
        gll16(ga0 + k0, la0);
        gll16(ga1 + k0, la1);
        gll16(gb0 + k0, lb0);
        gll16(gb1 + k0, lb1);
        __syncthreads();
        short8 af[4], bf4[4];
#pragma unroll
        for (int mt = 0; mt < 4; ++mt)
            af[mt] = *(const short8*)&As[(wr * 64 + mt * 16 + lm) * 32 + quad * 8];
#pragma unroll
        for (int nt = 0; nt < 4; ++nt)
            bf4[nt] = *(const short8*)&Bs[(wc * 64 + nt * 16 + lm) * 32 + quad * 8];
#pragma unroll
        for (int mt = 0; mt < 4; ++mt)
#pragma unroll
            for (int nt = 0; nt < 4; ++nt)
                acc[mt][nt] = __builtin_amdgcn_mfma_f32_16x16x32_bf16(
                    af[mt], bf4[nt], acc[mt][nt], 0, 0, 0);
    }
#pragma unroll
    for (int mt = 0; mt < 4; ++mt)
#pragma unroll
        for (int nt = 0; nt < 4; ++nt) {
            const int col = n0 + wc * 64 + nt * 16 + lm;
#pragma unroll
            for (int i = 0; i < 4; ++i) {
                const int row = m0 + wr * 64 + mt * 16 + quad * 4 + i;
                store_out(&C[(size_t)row * ldc + col], acc[mt][nt][i]);
            }
        }
}

// ---------------------------------------------------------------------------
// sims + fused topk: sims[b][m] = (qvec.e_m)/(|e_m|+1e-8); the LAST block to
// finish (device-scope atomic + threadfence) runs the register top-10 for both
// batches on waves 0/1. Grid (250, 2) — m never exceeds 999, no early return.
// ---------------------------------------------------------------------------
__global__ __launch_bounds__(256) void sims_topk(const float* __restrict__ lk,
                                                 const float* __restrict__ events,
                                                 float* __restrict__ sims,
                                                 int* __restrict__ topk,
                                                 int* __restrict__ done) {
    const int b = blockIdx.y;
    const int tid = threadIdx.x;
    const int wave = tid >> 6, lane = tid & 63;
    __shared__ float qv[1024];
    __shared__ int sLast;
    for (int i = tid; i < 1024; i += 256)
        qv[i] = lk[b * 1024 + i];
    __syncthreads();

    const int m = blockIdx.x * 4 + wave;   // < 1000 always
    const float* ev = &events[(size_t)m * 1024];
    float dot = 0.f, nrm = 0.f;
    for (int d = lane; d < 1024; d += 64) {
        float e = ev[d];
        dot += qv[d] * e;
        nrm += e * e;
    }
    for (int off = 32; off; off >>= 1) {
        dot += __shfl_down(dot, off);
        nrm += __shfl_down(nrm, off);
    }
    if (lane == 0) sims[b * 1024 + m] = dot / (sqrtf(nrm) + 1e-8f);

    // last-block-done -> topk (both batches)
    __threadfence();
    if (tid == 0) sLast = (atomicAdd(done, 1) == 499) ? 1 : 0;
    __syncthreads();
    if (!sLast) return;
    const int w = wave;
    if (w < 2) {
        const int base = lane * 16;
        float v[16];
#pragma unroll
        for (int j = 0; j < 16; ++j) {
            const int mm = base + j;
            v[j] = (mm < MEM_) ? sims[w * 1024 + mm] : -INFINITY;
        }
        for (int it = 0; it < KTOT; ++it) {
            float best = -INFINITY; int bi = 0x7fffffff;
#pragma unroll
            for (int j = 0; j < 16; ++j)
                if (v[j] > best) { best = v[j]; bi = base + j; }
            for (int off = 32; off; off >>= 1) {
                const float ob = __shfl_xor(best, off);
                const int   oi = __shfl_xor(bi, off);
                if (ob > best || (ob == best && oi < bi)) { best = ob; bi = oi; }
            }
            if (lane == 0) topk[w * KTOT + it] = bi;
#pragma unroll
            for (int j = 0; j < 16; ++j)
                if (base + j == bi) v[j] = -INFINITY;
        }
    }
}

// ---------------------------------------------------------------------------
// Flash attention, bf16 MFMA, persistent + work stealing (768 blocks, 1024
// items LPT order).
// R9: cross-tile software pipeline with DOUBLE-BUFFERED Ks/Vt:
//   iter kt: barrier | stage(kt->buf) + prefetch(kt+1) | barrier |
//            qk(kt)  ||  pv(kt-1, other buf)  | softmax(kt)
// Delayed PV is legal because the running max is FROZEN after mem+kt0 (no
// alpha rescale in the pipelined path) and Ps is wave-private (program order
// guarantees pv(kt-1) reads it before softmax(kt) overwrites).
// Ones-column l-trick, frozen-max, exact-underflow tile skip as in R8.
// ---------------------------------------------------------------------------
__global__ __launch_bounds__(256) void attn_mfma(
        const __hip_bfloat16* __restrict__ qkv,
        const float* __restrict__ events,
        const int* __restrict__ topk,
        const float* __restrict__ amask,
        __hip_bfloat16* __restrict__ out,
        int* __restrict__ ctr) {
    const int tid = threadIdx.x;
    const int wave = tid >> 6, lane = tid & 63;
    const int quad = lane >> 4, lm = lane & 15;

    const __hip_bfloat16* qf = qkv;
    const __hip_bfloat16* kf = qkv + 1024;
    const __hip_bfloat16* vf = qkv + 2048;

    __shared__ __hip_bfloat16 Ks[2][64 * LDK];
    __shared__ __hip_bfloat16 Vt[2][80 * LDK];  // [d][kcol]; rows 64..79 static (64=ones)
    __shared__ __hip_bfloat16 Ps[64 * LDK];     // wave-private rows
    __shared__ float colb[64];
    __shared__ float redb[4];
    __shared__ int sItem;

    const int va = tid & 31, vdc = tid >> 5;
    const int vtok0 = va * 2, vd0 = vdc * 8;

    // static ones/zero rows of Vt (l-accumulator trick) — both buffers, once
    for (int i = tid; i < 16 * LDK; i += 256) {
        const int r = i / LDK;
        const __hip_bfloat16 x = __float2bfloat16(r == 0 ? 1.0f : 0.0f);
        Vt[0][64 * LDK + i] = x;
        Vt[1][64 * LDK + i] = x;
    }

    for (;;) {
        __syncthreads();    // prev item's LDS readers done; also covers Vt init
        if (tid == 0) sItem = atomicAdd(ctr, 1);
        __syncthreads();
        const int n = sItem;
        if (n >= NITEMS) break;

        const int qt = 31 - (n >> 5);
        const int q0 = qt * 64;
        const int inner = n & 31;
        const int h = 15 - ((inner >> 1) & 15);
        const int b = inner & 1;
        const float slope = exp2f(-0.5f * (float)(h + 1));

        // ---- Q fragments straight into registers ----
        short8 qa[2];
        {
            const __hip_bfloat16* qsrc =
                &qf[((size_t)(b * S_ + q0 + wave * 16 + lm)) * 3072 + h * 64 + quad * 8];
            qa[0] = *(const short8*)qsrc;
            qa[1] = *(const short8*)(qsrc + 32);
        }
        // zero Vt[0] rows 0..63 (mem tile fills only 10 cols)
        for (int i = tid * 8; i < 64 * LDK; i += 256 * 8)
            *(int4*)&Vt[0][i] = make_int4(0, 0, 0, 0);
        __syncthreads();
        if (tid < 80) {     // 10 memory tokens (K rows 0..9; Vt cols 0..9)
            const int tok = tid >> 3, d0 = (tid & 7) * 8;
            const int ev = topk[b * KTOT + tok];
            const float* es = &events[(size_t)ev * 1024 + h * 64 + d0];
#pragma unroll
            for (int j = 0; j < 8; ++j) {
                __hip_bfloat16 x = __float2bfloat16(es[j]);
                Ks[0][tok * LDK + d0 + j] = x;
                Vt[0][(d0 + j) * LDK + tok] = x;
            }
        }
        __syncthreads();

        float m_[4], mshift[4];
        f32x4 Oa[5];        // Oa[4] = softmax denominator column
#pragma unroll
        for (int i = 0; i < 4; ++i) {
            m_[i] = -INFINITY;
            mshift[i] = -slope * (float)(q0 + wave * 16 + quad * 4 + i);
        }
#pragma unroll
        for (int nt = 0; nt < 5; ++nt) Oa[nt] = (f32x4){0.f, 0.f, 0.f, 0.f};

        short8 pk[2], pv0, pv1;
        float pam = 1.f;
        auto prefetchKV = [&](int kt) {
            const __hip_bfloat16* ks = &kf[((size_t)(b * S_ + kt * 64)) * 3072 + h * 64];
#pragma unroll
            for (int u = 0; u < 2; ++u) {
                int c = tid * 2 + u, row = c >> 3, off = (c & 7) * 8;
                pk[u] = *(const short8*)&ks[(size_t)row * 3072 + off];
            }
            const __hip_bfloat16* v0 =
                &vf[((size_t)(b * S_ + kt * 64 + vtok0)) * 3072 + h * 64 + vd0];
            pv0 = *(const short8*)v0;
            pv1 = *(const short8*)(v0 + 3072);
            if (tid < 64) pam = amask[b * S_ + kt * 64 + tid];
        };
        auto stageKV = [&](int kt, int buf) {
#pragma unroll
            for (int u = 0; u < 2; ++u) {
                int c = tid * 2 + u, row = c >> 3, off = (c & 7) * 8;
                *(short8*)&Ks[buf][row * LDK + off] = pk[u];
            }
#pragma unroll
            for (int j = 0; j < 8; ++j) {
                short2 pr; pr.x = pv0[j]; pr.y = pv1[j];
                *(short2*)&Vt[buf][(vd0 + j) * LDK + vtok0] = pr;
            }
            if (tid < 64)
                colb[tid] = fmaf(-slope, (float)(kt * 64 + tid), (1.f - pam) * NEG9);
        };

        auto qk = [&](f32x4* sa, int buf) {
#pragma unroll
            for (int nt = 0; nt < 4; ++nt) sa[nt] = (f32x4){0.f, 0.f, 0.f, 0.f};
#pragma unroll
            for (int ks2 = 0; ks2 < 2; ++ks2) {
#pragma unroll
                for (int nt = 0; nt < 4; ++nt) {
                    short8 bk = *(const short8*)&Ks[buf][(nt * 16 + lm) * LDK + ks2 * 32 + quad * 8];
                    sa[nt] = __builtin_amdgcn_mfma_f32_16x16x32_bf16(qa[ks2], bk, sa[nt], 0, 0, 0);
                }
            }
        };
        auto pv = [&](int buf) {
#pragma unroll
            for (int ks2 = 0; ks2 < 2; ++ks2) {
                short8 ap = *(const short8*)&Ps[(wave * 16 + lm) * LDK + ks2 * 32 + quad * 8];
#pragma unroll
                for (int nt = 0; nt < 5; ++nt) {   // nt=4: ones column -> l
                    short8 bv = *(const short8*)&Vt[buf][(nt * 16 + lm) * LDK + ks2 * 32 + quad * 8];
                    Oa[nt] = __builtin_amdgcn_mfma_f32_16x16x32_bf16(ap, bv, Oa[nt], 0, 0, 0);
                }
            }
        };

        auto softmax_online = [&](const f32x4* sa, int kt, bool diag) {
            float cb[4];
            if (kt >= 0) {
#pragma unroll
                for (int nt = 0; nt < 4; ++nt) cb[nt] = colb[nt * 16 + lm];
            }
#pragma unroll
            for (int i = 0; i < 4; ++i) {
                const int lr = wave * 16 + quad * 4 + i;
                const int rg = q0 + lr;
                float s[4];
#pragma unroll
                for (int nt = 0; nt < 4; ++nt) {
                    const int cc = nt * 16 + lm;
                    if (kt < 0) {
                        s[nt] = (cc < KTOT) ? fmaf(sa[nt][i], 0.125f, mshift[i]) : NEG9;
                    } else {
                        float v = fmaf(sa[nt][i], 0.125f, cb[nt]);
                        s[nt] = (diag && kt * 64 + cc > rg) ? NEG9 : v;
                    }
                }
                float rmax = fmaxf(fmaxf(s[0], s[1]), fmaxf(s[2], s[3]));
#pragma unroll
                for (int off = 1; off < 16; off <<= 1)
                    rmax = fmaxf(rmax, __shfl_xor(rmax, off, 16));
                const float newm = fmaxf(m_[i], rmax);
                const float al = __expf(m_[i] - newm);
                m_[i] = newm;
#pragma unroll
                for (int nt = 0; nt < 4; ++nt)
                    Ps[lr * LDK + nt * 16 + lm] = __float2bfloat16(__expf(s[nt] - newm));
#pragma unroll
                for (int nt = 0; nt < 5; ++nt)     // includes l-column
                    Oa[nt][i] *= al;
            }
        };

        auto softmax_fast = [&](const f32x4* sa, int cbase, bool diag) {
            float cb[4];
#pragma unroll
            for (int nt = 0; nt < 4; ++nt) cb[nt] = colb[nt * 16 + lm];
#pragma unroll
            for (int i = 0; i < 4; ++i) {
                const int lr = wave * 16 + quad * 4 + i;
                const float cm = m_[i];
                float p[4];
#pragma unroll
                for (int nt = 0; nt < 4; ++nt)
                    p[nt] = __expf(fmaf(sa[nt][i], 0.125f, cb[nt]) - cm);
                if (diag) {
                    const int rg = q0 + lr;
#pragma unroll
                    for (int nt = 0; nt < 4; ++nt)
                        if (cbase + nt * 16 + lm > rg) p[nt] = 0.f;
                }
#pragma unroll
                for (int nt = 0; nt < 4; ++nt)
                    Ps[lr * LDK + nt * 16 + lm] = __float2bfloat16(p[nt]);
            }
        };

        // ---- memory tile (online, buf0) ----
        prefetchKV(0);
        {
            f32x4 sa[4];
            qk(sa, 0);
            softmax_online(sa, -1, false);
            pv(0);
        }
        // ---- kt = 0 (online, buf1) ----
        __syncthreads();
        stageKV(0, 1);
        if (qt >= 1) prefetchKV(1);
        __syncthreads();
        {
            f32x4 sa[4];
            qk(sa, 1);
            softmax_online(sa, 0, qt == 0);
            pv(1);
        }

        // ---- freeze max; block-min(m) -> exact-underflow cutoff ----
        int ktend = 0;
        if (qt >= 1) {
            float mloc = fminf(fminf(m_[0], m_[1]), fminf(m_[2], m_[3]));
#pragma unroll
            for (int off = 1; off < 64; off <<= 1)
                mloc = fminf(mloc, __shfl_xor(mloc, off, 64));
            if (lane == 0) redb[wave] = mloc;
            __syncthreads();   // also guards buf0 restage below (mem readers done)
            const float mmin = fminf(fminf(redb[0], redb[1]), fminf(redb[2], redb[3]));
            ktend = min(qt, (int)((118.f - mmin) / (64.f * slope)));
            if (ktend < 1) ktend = 0;
        }

        // ---- pipelined tiles kt=1..ktend; buf(kt) = (kt+1)&1 ----
        if (ktend >= 1) {
            f32x4 sa[4];
            stageKV(1, 0);
            if (ktend >= 2) prefetchKV(2);
            __syncthreads();
            qk(sa, 0);
            softmax_fast(sa, 64, 1 == qt);
            for (int kt = 2; kt <= ktend; ++kt) {
                const int buf = (kt + 1) & 1;
                __syncthreads();             // readers of buf (tile kt-2) done
                stageKV(kt, buf);
                if (kt < ktend) prefetchKV(kt + 1);
                __syncthreads();
                qk(sa, buf);                 // tile kt
                pv(1 - buf);                 // tile kt-1 (Ps still holds kt-1)
                softmax_fast(sa, kt * 64, kt == qt);
            }
            pv((ktend + 1) & 1);             // drain last tile
        }

        // ---- epilogue: l lives in Oa[4] col 0 (lanes lm==0); broadcast ----
#pragma unroll
        for (int i = 0; i < 4; ++i) {
            const int lr = wave * 16 + quad * 4 + i;
            const float l = __shfl(Oa[4][i], (lane & 48));
            const float inv = 1.f / l;
            __hip_bfloat16* dst = &out[((size_t)(b * S_ + q0 + lr)) * 1024 + h * 64 + lm];
#pragma unroll
            for (int nt = 0; nt < 4; ++nt)
                dst[nt * 16] = __float2bfloat16(Oa[nt][i] * inv);
        }
    }
}

// ---------------------------------------------------------------------------
extern "C" void kernel_launch(void* const* d_in, const int* in_sizes, int n_in,
                              void* d_out, int out_size, void* d_ws, size_t ws_size,
                              hipStream_t stream) {
    const float* inputs = (const float*)d_in[0];
    const float* amask  = (const float*)d_in[1];
    const float* Wq     = (const float*)d_in[2];
    const float* Wk     = (const float*)d_in[3];
    const float* Wv     = (const float*)d_in[4];
    const float* Wo     = (const float*)d_in[5];
    const float* events = (const float*)d_in[6];
    float* out = (float*)d_out;

    // ws: Ax 8MB | Wt 8MB | qkv 24MB | ao 8MB | lk | sims | topk | ctr+done
    __hip_bfloat16* Ax  = (__hip_bfloat16*)d_ws;
    __hip_bfloat16* Wt  = Ax + (size_t)NROW * 1024;
    __hip_bfloat16* qkv = Wt + (size_t)4096 * 1024;
    __hip_bfloat16* ao  = qkv + (size_t)NROW * 3072;
    float* lk   = (float*)(ao + (size_t)NROW * 1024);
    float* sims = lk + 2 * 1024;
    int* topk   = (int*)(sims + 2 * 1024);
    int* ctr    = topk + B_ * KTOT;   // [0]=steal counter, [1]=sims-done

    dim3 blk(256);
    prep<<<3104, blk, 0, stream>>>(inputs, Wq, Wk, Wv, Wo, Ax, Wt, lk, ctr);
    sims_topk<<<dim3(250, B_), blk, 0, stream>>>(lk, events, sims, topk, ctr + 1);
    gemm_mfma<__hip_bfloat16><<<dim3(24, 32), blk, 0, stream>>>(Ax, Wt, qkv, 3072);
    attn_mfma<<<768, blk, 0, stream>>>(qkv, events, topk, amask, ao, ctr);
    gemm_mfma<float><<<dim3(8, 32), blk, 0, stream>>>(
        ao, Wt + (size_t)3072 * 1024, out, 1024);
}